// Round 1
// baseline (977.979 us; speedup 1.0000x reference)
//
#include <hip/hip_runtime.h>

#define BATCH 999
#define HID 1024
#define SEQ 160

#define BT 64   // batches per block tile
#define KT 128  // k columns per block tile
#define HT 32   // h staged per LDS iteration
#define HSPLIT 4
#define HPER (HID / HSPLIT)  // 256 h per block

// Fused: tmp = C @ M (tile), then partial dot with R, atomicAdd into ws.
__global__ __launch_bounds__(256, 2)
void dots_kernel(const float* __restrict__ Cg, const float* __restrict__ Rg,
                 const float* __restrict__ Mg, float* __restrict__ ws)
{
    __shared__ float sC[BT][HT];   // 8 KB
    __shared__ float sM[HT][KT];   // 16 KB

    const int tid = threadIdx.x;
    const int tx  = tid & 31;   // k-thread: covers k0 + 4*tx .. +3
    const int ty  = tid >> 5;   // b-thread: covers b0 + 8*ty .. +7
    const int k0  = blockIdx.x * KT;
    const int b0  = blockIdx.y * BT;
    const int h0  = blockIdx.z * HPER;

    float acc[8][4];
    #pragma unroll
    for (int i = 0; i < 8; ++i)
        #pragma unroll
        for (int j = 0; j < 4; ++j) acc[i][j] = 0.f;

    for (int t = 0; t < HPER / HT; ++t) {
        const int hbase = h0 + t * HT;

        // stage C tile: 64 rows x 32 floats = 512 float4, 2 per thread
        #pragma unroll
        for (int i = 0; i < 2; ++i) {
            int f  = tid + 256 * i;
            int b  = f >> 3;             // 0..63
            int h4 = (f & 7) << 2;       // 0,4,...,28
            float4 v = make_float4(0.f, 0.f, 0.f, 0.f);
            int gb = b0 + b;
            if (gb < BATCH)
                v = *(const float4*)(Cg + ((size_t)gb * SEQ + SEQ - 1) * HID + hbase + h4);
            *(float4*)&sC[b][h4] = v;
        }
        // stage M tile: 32 rows x 128 floats = 1024 float4, 4 per thread
        #pragma unroll
        for (int i = 0; i < 4; ++i) {
            int f  = tid + 256 * i;
            int r  = f >> 5;             // 0..31
            int c4 = (f & 31) << 2;      // 0..124
            *(float4*)&sM[r][c4] =
                *(const float4*)(Mg + (size_t)(hbase + r) * HID + k0 + c4);
        }
        __syncthreads();

        #pragma unroll
        for (int m = 0; m < HT / 4; ++m) {
            const int hh = m * 4;
            float4 c4[8];
            #pragma unroll
            for (int i = 0; i < 8; ++i)
                c4[i] = *(float4*)&sC[ty * 8 + i][hh];
            #pragma unroll
            for (int j2 = 0; j2 < 4; ++j2) {
                float4 mv = *(float4*)&sM[hh + j2][tx * 4];
                #pragma unroll
                for (int i = 0; i < 8; ++i) {
                    float cs = (j2 == 0) ? c4[i].x : (j2 == 1) ? c4[i].y
                             : (j2 == 2) ? c4[i].z : c4[i].w;
                    acc[i][0] += cs * mv.x;
                    acc[i][1] += cs * mv.y;
                    acc[i][2] += cs * mv.z;
                    acc[i][3] += cs * mv.w;
                }
            }
        }
        __syncthreads();
    }

    // epilogue: multiply by r[b, k0+4tx..+3], reduce over the 32 k-lanes
    #pragma unroll
    for (int i = 0; i < 8; ++i) {
        const int gb = b0 + ty * 8 + i;
        float4 rv = make_float4(0.f, 0.f, 0.f, 0.f);
        if (gb < BATCH)
            rv = *(const float4*)(Rg + ((size_t)gb * SEQ + SEQ - 1) * HID + k0 + tx * 4);
        float p = acc[i][0] * rv.x + acc[i][1] * rv.y
                + acc[i][2] * rv.z + acc[i][3] * rv.w;
        // butterfly over 32-lane k-groups (masks < 32 stay within each half-wave)
        #pragma unroll
        for (int m = 1; m < 32; m <<= 1) p += __shfl_xor(p, m, 64);
        if (tx == 0 && gb < BATCH) atomicAdd(&ws[gb], p);
    }
}

__global__ void sigmoid_kernel(const float* __restrict__ ws,
                               float* __restrict__ out, int n)
{
    int i = blockIdx.x * blockDim.x + threadIdx.x;
    if (i < n) {
        float d = ws[i];
        out[i] = 1.f / (1.f + __expf(-d));
    }
}

extern "C" void kernel_launch(void* const* d_in, const int* in_sizes, int n_in,
                              void* d_out, int out_size, void* d_ws, size_t ws_size,
                              hipStream_t stream) {
    const float* ctx = (const float*)d_in[0];
    const float* rsp = (const float*)d_in[1];
    const float* M   = (const float*)d_in[2];
    float* out = (float*)d_out;
    float* ws  = (float*)d_ws;

    hipMemsetAsync(ws, 0, BATCH * sizeof(float), stream);

    dim3 grid(HID / KT, (BATCH + BT - 1) / BT, HSPLIT);  // 8 x 16 x 4 = 512 blocks
    dots_kernel<<<grid, 256, 0, stream>>>(ctx, rsp, M, ws);

    sigmoid_kernel<<<(BATCH + 255) / 256, 256, 0, stream>>>(ws, out, BATCH);
}